// Round 4
// baseline (313.269 us; speedup 1.0000x reference)
//
#include <hip/hip_runtime.h>
#include <math.h>

// Problem constants
constexpr int B  = 4;
constexpr int S  = 2048;
constexpr int DM = 1024;
constexpr int DK = 128;
constexpr int BS = B * S;

static constexpr float SCALE = 0.08838834764831845f; // 1/sqrt(128)

typedef __attribute__((ext_vector_type(8))) short bf16x8;
typedef __attribute__((ext_vector_type(4))) float f32x4;

__device__ __forceinline__ unsigned short f2bf(float x) {
  unsigned u = __float_as_uint(x);
  unsigned r = (u + 0x7FFFu + ((u >> 16) & 1u)) >> 16;   // RNE
  return (unsigned short)r;
}
__device__ __forceinline__ float bf2f(unsigned short h) {
  return __uint_as_float(((unsigned)h) << 16);
}

__device__ __forceinline__ void gload16(const void* g, void* l) {
  __builtin_amdgcn_global_load_lds(
      (const __attribute__((address_space(1))) void*)g,
      (__attribute__((address_space(3))) void*)l, 16, 0, 0);
}

// ---------------------------------------------------------------------------
// Prep 1: vin fp32 -> Ah (bf16 RNE) + Al (bf16 of residual), row-major [BS][DM]
// ---------------------------------------------------------------------------
__global__ __launch_bounds__(256) void cvt_hilo(
    const float* __restrict__ x, unsigned short* __restrict__ hi,
    unsigned short* __restrict__ lo)
{
  const size_t idx = (size_t)blockIdx.x * 256 + threadIdx.x;  // float4 index
  const float4 v = ((const float4*)x)[idx];
  ushort4 h, l;
  h.x = f2bf(v.x); l.x = f2bf(v.x - bf2f(h.x));
  h.y = f2bf(v.y); l.y = f2bf(v.y - bf2f(h.y));
  h.z = f2bf(v.z); l.z = f2bf(v.z - bf2f(h.z));
  h.w = f2bf(v.w); l.w = f2bf(v.w - bf2f(h.w));
  ((ushort4*)hi)[idx] = h;
  ((ushort4*)lo)[idx] = l;
}

// ---------------------------------------------------------------------------
// Prep 2: w_q/w_k/w_v [1024][128] fp32 -> Wt hi/lo bf16 [384][1024] (B^T layout,
// rows n = p*128 + c).  Tiny (1.5 MB); strided reads hit L2.
// ---------------------------------------------------------------------------
__global__ void cvtw_kernel(const float* __restrict__ wq, const float* __restrict__ wk,
                            const float* __restrict__ wv,
                            unsigned short* __restrict__ Wth, unsigned short* __restrict__ Wtl)
{
  const int n = blockIdx.x;            // 0..383
  const int p = n >> 7, c = n & 127;
  const float* w = (p == 0) ? wq : (p == 1) ? wk : wv;
  for (int k = threadIdx.x; k < DM; k += 256) {
    const float x = w[(size_t)k * DK + c];
    const unsigned short h = f2bf(x);
    Wth[(size_t)n * DM + k] = h;
    Wtl[(size_t)n * DM + k] = f2bf(x - bf2f(h));
  }
}

// ---------------------------------------------------------------------------
// Kernel A: qkv = vin @ [wq|wk|wv] via split-bf16 MFMA (3 products).
// Tile 64x64, BK=64, 4 waves in 2x2, each wave 32x32 (2x2 frags of 16x16x32).
// global_load_lds width-16 staging, linear LDS (m97 structure).
// ---------------------------------------------------------------------------
__global__ __launch_bounds__(256) void proj_mfma(
    const unsigned short* __restrict__ Ah, const unsigned short* __restrict__ Al,
    const unsigned short* __restrict__ Wh, const unsigned short* __restrict__ Wl,
    float* __restrict__ qkv)
{
  __shared__ unsigned short Ash[2][64 * 64];
  __shared__ unsigned short Wsh[2][64 * 64];

  const int r0 = blockIdx.x * 64;      // M tile (8192/64 = 128)
  const int n0 = blockIdx.y * 64;      // N tile (384/64 = 6)
  const int t  = threadIdx.x;
  const int l  = t & 63, w = t >> 6;
  const int wm = w >> 1, wn = w & 1;   // 2x2 wave grid
  const int fr = l & 15, ko = (l >> 4) * 8;

  f32x4 acc[2][2] = {};

  for (int k0 = 0; k0 < DM; k0 += 64) {
    #pragma unroll
    for (int i = 0; i < 2; ++i) {
      const int flat = t + i * 256;          // 512 16B segments per tile
      const int row = flat >> 3, sg = flat & 7;
      const size_t ga = (size_t)(r0 + row) * DM + k0 + sg * 8;
      const size_t gw = (size_t)(n0 + row) * DM + k0 + sg * 8;
      gload16(Ah + ga, &Ash[0][flat * 8]);
      gload16(Al + ga, &Ash[1][flat * 8]);
      gload16(Wh + gw, &Wsh[0][flat * 8]);
      gload16(Wl + gw, &Wsh[1][flat * 8]);
    }
    __syncthreads();

    #pragma unroll
    for (int kk = 0; kk < 2; ++kk) {
      bf16x8 ah[2], al[2], bh[2], bl[2];
      #pragma unroll
      for (int im = 0; im < 2; ++im) {
        const int off = (wm * 32 + im * 16 + fr) * 64 + kk * 32 + ko;
        ah[im] = *(const bf16x8*)&Ash[0][off];
        al[im] = *(const bf16x8*)&Ash[1][off];
      }
      #pragma unroll
      for (int in = 0; in < 2; ++in) {
        const int off = (wn * 32 + in * 16 + fr) * 64 + kk * 32 + ko;
        bh[in] = *(const bf16x8*)&Wsh[0][off];
        bl[in] = *(const bf16x8*)&Wsh[1][off];
      }
      #pragma unroll
      for (int im = 0; im < 2; ++im)
        #pragma unroll
        for (int in = 0; in < 2; ++in) {
          acc[im][in] = __builtin_amdgcn_mfma_f32_16x16x32_bf16(ah[im], bh[in], acc[im][in], 0, 0, 0);
          acc[im][in] = __builtin_amdgcn_mfma_f32_16x16x32_bf16(ah[im], bl[in], acc[im][in], 0, 0, 0);
          acc[im][in] = __builtin_amdgcn_mfma_f32_16x16x32_bf16(al[im], bh[in], acc[im][in], 0, 0, 0);
        }
    }
    __syncthreads();
  }

  // Epilogue: C/D layout col = lane&15, row = (lane>>4)*4 + reg  [m89-verified]
  const int crow = (l >> 4) * 4;
  #pragma unroll
  for (int im = 0; im < 2; ++im)
    #pragma unroll
    for (int in = 0; in < 2; ++in) {
      const int n = n0 + wn * 32 + in * 16 + fr;
      float* dst = qkv + (size_t)(n >> 7) * ((size_t)BS * DK) + (n & 127);
      #pragma unroll
      for (int r = 0; r < 4; ++r) {
        const int m = r0 + wm * 32 + im * 16 + crow + r;
        dst[(size_t)m * DK] = acc[im][in][r];
      }
    }
}

// ---------------------------------------------------------------------------
// Kernel B: raw scores for lower-tri tiles (fp32 vector, float4 LDS reads).
// Full K=128 staged once; 64x64 tile; micro-tile 4x4 (cols tx+16j).
// ---------------------------------------------------------------------------
__global__ __launch_bounds__(256) void scores_kernel(
    const float* __restrict__ qkv, float* __restrict__ att)
{
  const int st = blockIdx.x, qt = blockIdx.y, b = blockIdx.z;
  if (qt < st) return;
  const int q0 = qt * 64, s0 = st * 64;
  const float* qm = qkv + (size_t)b * S * DK;
  const float* km = qkv + (size_t)BS * DK + (size_t)b * S * DK;

  __shared__ float Qs[64][132];
  __shared__ float Ks[64][132];

  const int t  = threadIdx.x;
  const int ty = t >> 4, tx = t & 15;
  float acc[4][4] = {};

  #pragma unroll
  for (int i = 0; i < 8; ++i) {
    const int flat = t + i * 256;           // 2048 float4 per operand
    const int row = flat >> 5, c4 = (flat & 31) * 4;
    *(float4*)&Qs[row][c4] = *(const float4*)&qm[(size_t)(q0 + row) * DK + c4];
    *(float4*)&Ks[row][c4] = *(const float4*)&km[(size_t)(s0 + row) * DK + c4];
  }
  __syncthreads();

  #pragma unroll 2
  for (int kk = 0; kk < DK; kk += 4) {
    float4 a4[4], b4[4];
    #pragma unroll
    for (int i = 0; i < 4; ++i) a4[i] = *(const float4*)&Qs[ty * 4 + i][kk];
    #pragma unroll
    for (int j = 0; j < 4; ++j) b4[j] = *(const float4*)&Ks[tx + 16 * j][kk];
    #pragma unroll
    for (int i = 0; i < 4; ++i)
      #pragma unroll
      for (int j = 0; j < 4; ++j) {
        acc[i][j] += a4[i].x * b4[j].x;
        acc[i][j] += a4[i].y * b4[j].y;
        acc[i][j] += a4[i].z * b4[j].z;
        acc[i][j] += a4[i].w * b4[j].w;
      }
  }

  float* attb = att + (size_t)b * S * S;
  #pragma unroll
  for (int i = 0; i < 4; ++i) {
    const size_t qi = q0 + ty * 4 + i;
    #pragma unroll
    for (int j = 0; j < 4; ++j)
      attb[qi * S + s0 + tx + 16 * j] = acc[i][j] * SCALE;
  }
}

// ---------------------------------------------------------------------------
// Kernel C: column softmax (over q, causal q>=s) — unchanged structure
// ---------------------------------------------------------------------------
__global__ __launch_bounds__(256) void colstats_kernel(
    const float* __restrict__ att, float* __restrict__ pm, float* __restrict__ ps)
{
  const int s  = blockIdx.x * 256 + threadIdx.x;
  const int ch = blockIdx.y, b = blockIdx.z;
  const float* attb = att + (size_t)b * S * S;
  const int qlo = ch * 256, qhi = qlo + 256;
  float m = -INFINITY, sum = 0.f;
  for (int q = qlo; q < qhi; ++q) {
    if (q >= s) {
      const float x  = attb[(size_t)q * S + s];
      const float mn = fmaxf(m, x);
      sum = sum * __expf(m - mn) + __expf(x - mn);
      m = mn;
    }
  }
  const size_t idx = ((size_t)b * 8 + ch) * S + s;
  pm[idx] = m;
  ps[idx] = sum;
}

__global__ void colcombine_kernel(const float* __restrict__ pm, const float* __restrict__ ps,
                                  float* __restrict__ cm, float* __restrict__ cinv)
{
  const int s = blockIdx.x * 256 + threadIdx.x;
  const int b = blockIdx.y;
  float m = -INFINITY;
  for (int ch = 0; ch < 8; ++ch)
    m = fmaxf(m, pm[((size_t)b * 8 + ch) * S + s]);
  float sum = 0.f;
  for (int ch = 0; ch < 8; ++ch) {
    const size_t i = ((size_t)b * 8 + ch) * S + s;
    sum += ps[i] * __expf(pm[i] - m);
  }
  cm[(size_t)b * S + s]   = m;
  cinv[(size_t)b * S + s] = 1.f / sum;
}

__global__ __launch_bounds__(256) void colnorm_kernel(
    float* __restrict__ att, const float* __restrict__ cm, const float* __restrict__ cinv)
{
  const int s  = blockIdx.x * 256 + threadIdx.x;
  const int qt = blockIdx.y, b = blockIdx.z;
  float* attb = att + (size_t)b * S * S;
  const float m   = cm[(size_t)b * S + s];
  const float inv = cinv[(size_t)b * S + s];
  const int q0 = qt * 64;
  for (int q = q0; q < q0 + 64; ++q) {
    const size_t idx = (size_t)q * S + s;
    float x = 0.f;
    if (q >= s) x = __expf(attb[idx] - m) * inv;
    attb[idx] = x;
  }
}

// ---------------------------------------------------------------------------
// Kernel D: out = att @ v (causal; att==0 above diag).  fp32 vector.
// Tile 32q x 128c, micro-tile 4q x 4 contiguous c (float4 stores).
// ---------------------------------------------------------------------------
__global__ __launch_bounds__(256) void out_kernel(
    const float* __restrict__ att, const float* __restrict__ qkv, float* __restrict__ out)
{
  const int qt = blockIdx.x, b = blockIdx.y;
  const int q0 = qt * 32;
  const float* attb = att + (size_t)b * S * S;
  const float* vm   = qkv + 2ull * BS * DK + (size_t)b * S * DK;

  __shared__ float As[32][68];
  __shared__ float Vs[64][132];

  const int t  = threadIdx.x;
  const int ty = t >> 5, tx = t & 31;      // rows ty*4+i, cols tx*4..tx*4+3
  float4 acc4[4] = {};

  for (int s0 = 0; s0 < q0 + 32; s0 += 64) {
    #pragma unroll
    for (int i = 0; i < 2; ++i) {
      const int flat = t + i * 256;        // 512 float4
      const int row = flat >> 4, c4 = (flat & 15) * 4;
      *(float4*)&As[row][c4] = *(const float4*)&attb[(size_t)(q0 + row) * S + s0 + c4];
    }
    #pragma unroll
    for (int i = 0; i < 8; ++i) {
      const int flat = t + i * 256;        // 2048 float4
      const int row = flat >> 5, c4 = (flat & 31) * 4;
      *(float4*)&Vs[row][c4] = *(const float4*)&vm[(size_t)(s0 + row) * DK + c4];
    }
    __syncthreads();

    #pragma unroll 2
    for (int kk = 0; kk < 64; kk += 4) {
      const float4 v0 = *(const float4*)&Vs[kk + 0][tx * 4];
      const float4 v1 = *(const float4*)&Vs[kk + 1][tx * 4];
      const float4 v2 = *(const float4*)&Vs[kk + 2][tx * 4];
      const float4 v3 = *(const float4*)&Vs[kk + 3][tx * 4];
      #pragma unroll
      for (int i = 0; i < 4; ++i) {
        const float4 a4 = *(const float4*)&As[ty * 4 + i][kk];
        acc4[i].x += a4.x * v0.x; acc4[i].y += a4.x * v0.y; acc4[i].z += a4.x * v0.z; acc4[i].w += a4.x * v0.w;
        acc4[i].x += a4.y * v1.x; acc4[i].y += a4.y * v1.y; acc4[i].z += a4.y * v1.z; acc4[i].w += a4.y * v1.w;
        acc4[i].x += a4.z * v2.x; acc4[i].y += a4.z * v2.y; acc4[i].z += a4.z * v2.z; acc4[i].w += a4.z * v2.w;
        acc4[i].x += a4.w * v3.x; acc4[i].y += a4.w * v3.y; acc4[i].z += a4.w * v3.z; acc4[i].w += a4.w * v3.w;
      }
    }
    __syncthreads();
  }

  #pragma unroll
  for (int i = 0; i < 4; ++i)
    *(float4*)&out[((size_t)b * S + q0 + ty * 4 + i) * DK + tx * 4] = acc4[i];
}

// ---------------------------------------------------------------------------
extern "C" void kernel_launch(void* const* d_in, const int* in_sizes, int n_in,
                              void* d_out, int out_size, void* d_ws, size_t ws_size,
                              hipStream_t stream)
{
  const float* vin = (const float*)d_in[0];
  const float* wq  = (const float*)d_in[1];
  const float* wk  = (const float*)d_in[2];
  const float* wv  = (const float*)d_in[3];

  float* out = (float*)d_out;
  float* att = out + (size_t)B * S * DK;     // attention output region (64 MB)

  // bf16 copies live INSIDE the att region (dead before scores_kernel writes it):
  // Ah 16MB + Al 16MB + Wth/Wtl 1.5MB = 33.5MB < 64MB.
  unsigned short* Ah  = (unsigned short*)att;
  unsigned short* Al  = Ah  + (size_t)BS * DM;
  unsigned short* Wth = Al  + (size_t)BS * DM;
  unsigned short* Wtl = Wth + (size_t)384 * DM;

  float* qkv  = (float*)d_ws;                // 3 * BS * 128 fp32
  float* pm   = qkv + 3ull * BS * DK;        // B * 8 * S
  float* ps   = pm + 8ull * B * S;
  float* cm   = ps + 8ull * B * S;
  float* cinv = cm + (size_t)B * S;

  cvt_hilo         <<<dim3(BS * DM / 1024),     256, 0, stream>>>(vin, Ah, Al);
  cvtw_kernel      <<<dim3(384),                256, 0, stream>>>(wq, wk, wv, Wth, Wtl);
  proj_mfma        <<<dim3(128, 6),             256, 0, stream>>>(Ah, Al, Wth, Wtl, qkv);
  scores_kernel    <<<dim3(S / 64, S / 64, B),  256, 0, stream>>>(qkv, att);
  colstats_kernel  <<<dim3(S / 256, 8, B),      256, 0, stream>>>(att, pm, ps);
  colcombine_kernel<<<dim3(S / 256, B),         256, 0, stream>>>(pm, ps, cm, cinv);
  colnorm_kernel   <<<dim3(S / 256, S / 64, B), 256, 0, stream>>>(att, cm, cinv);
  out_kernel       <<<dim3(S / 32, B),          256, 0, stream>>>(att, qkv, out);
}

// Round 5
// 251.988 us; speedup vs baseline: 1.2432x; 1.2432x over previous
//
#include <hip/hip_runtime.h>
#include <math.h>

// Problem constants
constexpr int B  = 4;
constexpr int S  = 2048;
constexpr int DM = 1024;
constexpr int DK = 128;
constexpr int BS = B * S;

static constexpr float SCALE = 0.08838834764831845f; // 1/sqrt(128)

typedef __attribute__((ext_vector_type(8))) short bf16x8;
typedef __attribute__((ext_vector_type(4))) float f32x4;

__device__ __forceinline__ unsigned short f2bf(float x) {
  unsigned u = __float_as_uint(x);
  unsigned r = (u + 0x7FFFu + ((u >> 16) & 1u)) >> 16;   // RNE
  return (unsigned short)r;
}
__device__ __forceinline__ float bf2f(unsigned short h) {
  return __uint_as_float(((unsigned)h) << 16);
}

__device__ __forceinline__ void gload16(const void* g, void* l) {
  __builtin_amdgcn_global_load_lds(
      (const __attribute__((address_space(1))) void*)g,
      (__attribute__((address_space(3))) void*)l, 16, 0, 0);
}

// ---------------------------------------------------------------------------
// Prep 1: vin fp32 -> Ah (bf16 RNE) + Al (bf16 of residual), row-major [BS][DM]
// ---------------------------------------------------------------------------
__global__ __launch_bounds__(256) void cvt_hilo(
    const float* __restrict__ x, unsigned short* __restrict__ hi,
    unsigned short* __restrict__ lo)
{
  const size_t idx = (size_t)blockIdx.x * 256 + threadIdx.x;  // float4 index
  const float4 v = ((const float4*)x)[idx];
  ushort4 h, l;
  h.x = f2bf(v.x); l.x = f2bf(v.x - bf2f(h.x));
  h.y = f2bf(v.y); l.y = f2bf(v.y - bf2f(h.y));
  h.z = f2bf(v.z); l.z = f2bf(v.z - bf2f(h.z));
  h.w = f2bf(v.w); l.w = f2bf(v.w - bf2f(h.w));
  ((ushort4*)hi)[idx] = h;
  ((ushort4*)lo)[idx] = l;
}

// ---------------------------------------------------------------------------
// Prep 2: w_q/w_k/w_v [1024][128] fp32 -> Wt hi/lo bf16 [384][1024] (B^T)
// ---------------------------------------------------------------------------
__global__ void cvtw_kernel(const float* __restrict__ wq, const float* __restrict__ wk,
                            const float* __restrict__ wv,
                            unsigned short* __restrict__ Wth, unsigned short* __restrict__ Wtl)
{
  const int n = blockIdx.x;            // 0..383
  const int p = n >> 7, c = n & 127;
  const float* w = (p == 0) ? wq : (p == 1) ? wk : wv;
  for (int k = threadIdx.x; k < DM; k += 256) {
    const float x = w[(size_t)k * DK + c];
    const unsigned short h = f2bf(x);
    Wth[(size_t)n * DM + k] = h;
    Wtl[(size_t)n * DM + k] = f2bf(x - bf2f(h));
  }
}

// ---------------------------------------------------------------------------
// Kernel A: qkv = vin @ [wq|wk|wv] via split-bf16 MFMA (3 products).
// ---------------------------------------------------------------------------
__global__ __launch_bounds__(256) void proj_mfma(
    const unsigned short* __restrict__ Ah, const unsigned short* __restrict__ Al,
    const unsigned short* __restrict__ Wh, const unsigned short* __restrict__ Wl,
    float* __restrict__ qkv)
{
  __shared__ unsigned short Ash[2][64 * 64];
  __shared__ unsigned short Wsh[2][64 * 64];

  const int r0 = blockIdx.x * 64;      // M tile (8192/64 = 128)
  const int n0 = blockIdx.y * 64;      // N tile (384/64 = 6)
  const int t  = threadIdx.x;
  const int l  = t & 63, w = t >> 6;
  const int wm = w >> 1, wn = w & 1;   // 2x2 wave grid
  const int fr = l & 15, ko = (l >> 4) * 8;

  f32x4 acc[2][2] = {};

  for (int k0 = 0; k0 < DM; k0 += 64) {
    #pragma unroll
    for (int i = 0; i < 2; ++i) {
      const int flat = t + i * 256;          // 512 16B segments per tile
      const int row = flat >> 3, sg = flat & 7;
      const size_t ga = (size_t)(r0 + row) * DM + k0 + sg * 8;
      const size_t gw = (size_t)(n0 + row) * DM + k0 + sg * 8;
      gload16(Ah + ga, &Ash[0][flat * 8]);
      gload16(Al + ga, &Ash[1][flat * 8]);
      gload16(Wh + gw, &Wsh[0][flat * 8]);
      gload16(Wl + gw, &Wsh[1][flat * 8]);
    }
    __syncthreads();

    #pragma unroll
    for (int kk = 0; kk < 2; ++kk) {
      bf16x8 ah[2], al[2], bh[2], bl[2];
      #pragma unroll
      for (int im = 0; im < 2; ++im) {
        const int off = (wm * 32 + im * 16 + fr) * 64 + kk * 32 + ko;
        ah[im] = *(const bf16x8*)&Ash[0][off];
        al[im] = *(const bf16x8*)&Ash[1][off];
      }
      #pragma unroll
      for (int in = 0; in < 2; ++in) {
        const int off = (wn * 32 + in * 16 + fr) * 64 + kk * 32 + ko;
        bh[in] = *(const bf16x8*)&Wsh[0][off];
        bl[in] = *(const bf16x8*)&Wsh[1][off];
      }
      #pragma unroll
      for (int im = 0; im < 2; ++im)
        #pragma unroll
        for (int in = 0; in < 2; ++in) {
          acc[im][in] = __builtin_amdgcn_mfma_f32_16x16x32_bf16(ah[im], bh[in], acc[im][in], 0, 0, 0);
          acc[im][in] = __builtin_amdgcn_mfma_f32_16x16x32_bf16(ah[im], bl[in], acc[im][in], 0, 0, 0);
          acc[im][in] = __builtin_amdgcn_mfma_f32_16x16x32_bf16(al[im], bh[in], acc[im][in], 0, 0, 0);
        }
    }
    __syncthreads();
  }

  // Epilogue: C/D layout col = lane&15, row = (lane>>4)*4 + reg
  const int crow = (l >> 4) * 4;
  #pragma unroll
  for (int im = 0; im < 2; ++im)
    #pragma unroll
    for (int in = 0; in < 2; ++in) {
      const int n = n0 + wn * 32 + in * 16 + fr;
      float* dst = qkv + (size_t)(n >> 7) * ((size_t)BS * DK) + (n & 127);
      #pragma unroll
      for (int r = 0; r < 4; ++r) {
        const int m = r0 + wm * 32 + im * 16 + crow + r;
        dst[(size_t)m * DK] = acc[im][in][r];
      }
    }
}

// ---------------------------------------------------------------------------
// Kernel B: raw scores for lower-tri tiles + fused per-tile column stats.
// Writes raw (scaled) scores to att and per-(qt-chunk, column) online
// softmax partials pm/ps (32 chunks of 64 rows).
// ---------------------------------------------------------------------------
__global__ __launch_bounds__(256) void scores_kernel(
    const float* __restrict__ qkv, float* __restrict__ att,
    float* __restrict__ pm, float* __restrict__ ps)
{
  const int st = blockIdx.x, qt = blockIdx.y, b = blockIdx.z;
  if (qt < st) return;
  const int q0 = qt * 64, s0 = st * 64;
  const float* qm = qkv + (size_t)b * S * DK;
  const float* km = qkv + (size_t)BS * DK + (size_t)b * S * DK;

  __shared__ float Qs[64][132];
  __shared__ float Ks[64][132];

  const int t  = threadIdx.x;
  const int ty = t >> 4, tx = t & 15;
  float acc[4][4] = {};

  #pragma unroll
  for (int i = 0; i < 8; ++i) {
    const int flat = t + i * 256;           // 2048 float4 per operand
    const int row = flat >> 5, c4 = (flat & 31) * 4;
    *(float4*)&Qs[row][c4] = *(const float4*)&qm[(size_t)(q0 + row) * DK + c4];
    *(float4*)&Ks[row][c4] = *(const float4*)&km[(size_t)(s0 + row) * DK + c4];
  }
  __syncthreads();

  #pragma unroll 2
  for (int kk = 0; kk < DK; kk += 4) {
    float4 a4[4], b4[4];
    #pragma unroll
    for (int i = 0; i < 4; ++i) a4[i] = *(const float4*)&Qs[ty * 4 + i][kk];
    #pragma unroll
    for (int j = 0; j < 4; ++j) b4[j] = *(const float4*)&Ks[tx + 16 * j][kk];
    #pragma unroll
    for (int i = 0; i < 4; ++i)
      #pragma unroll
      for (int j = 0; j < 4; ++j) {
        acc[i][j] += a4[i].x * b4[j].x;
        acc[i][j] += a4[i].y * b4[j].y;
        acc[i][j] += a4[i].z * b4[j].z;
        acc[i][j] += a4[i].w * b4[j].w;
      }
  }

  // scale + write raw scores (entries above diagonal inside the diagonal
  // tile are garbage-but-finite; pass 2 never uses them)
  float* attb = att + (size_t)b * S * S;
  #pragma unroll
  for (int i = 0; i < 4; ++i) {
    const size_t qi = q0 + ty * 4 + i;
    #pragma unroll
    for (int j = 0; j < 4; ++j) {
      acc[i][j] *= SCALE;
      attb[qi * S + s0 + tx + 16 * j] = acc[i][j];
    }
  }

  // ---- fused column stats (softmax over q within this 64-row chunk) ----
  __syncthreads();                       // all Qs/Ks reads done -> reuse LDS
  float* Rm = &Qs[0][0];                 // [64 cols][17]
  float* Re = Rm + 64 * 17;

  const bool diag = (st == qt);
  #pragma unroll
  for (int j = 0; j < 4; ++j) {
    const int col = tx + 16 * j;
    const int sg  = s0 + col;
    float mt = -INFINITY;
    #pragma unroll
    for (int i = 0; i < 4; ++i) {
      const int qg = q0 + ty * 4 + i;
      if (!diag || qg >= sg) mt = fmaxf(mt, acc[i][j]);
    }
    float et = 0.f;
    if (mt > -INFINITY) {
      #pragma unroll
      for (int i = 0; i < 4; ++i) {
        const int qg = q0 + ty * 4 + i;
        if (!diag || qg >= sg) et += __expf(acc[i][j] - mt);
      }
    }
    Rm[col * 17 + ty] = mt;
    Re[col * 17 + ty] = et;
  }
  __syncthreads();

  if (t < 64) {
    float m = -INFINITY;
    #pragma unroll
    for (int y = 0; y < 16; ++y) m = fmaxf(m, Rm[t * 17 + y]);
    float sum = 0.f;
    #pragma unroll
    for (int y = 0; y < 16; ++y) {
      const float mm = Rm[t * 17 + y];
      if (mm > -INFINITY) sum += Re[t * 17 + y] * __expf(mm - m);
    }
    const size_t o = ((size_t)(b * 32 + qt)) * S + s0 + t;
    pm[o] = m;
    ps[o] = sum;
  }
}

// ---------------------------------------------------------------------------
// Kernel C: combine 32 row-chunk partials -> per-column max m and 1/sum.
// Chunks qt < s/64 were never computed (fully masked) and are skipped.
// ---------------------------------------------------------------------------
__global__ void colcombine_kernel(const float* __restrict__ pm, const float* __restrict__ ps,
                                  float* __restrict__ cm, float* __restrict__ cinv)
{
  const int s = blockIdx.x * 256 + threadIdx.x;
  const int b = blockIdx.y;
  const int ch0 = s >> 6;
  float m = -INFINITY;
  for (int ch = ch0; ch < 32; ++ch)
    m = fmaxf(m, pm[((size_t)(b * 32 + ch)) * S + s]);
  float sum = 0.f;
  for (int ch = ch0; ch < 32; ++ch) {
    const size_t i = ((size_t)(b * 32 + ch)) * S + s;
    sum += ps[i] * __expf(pm[i] - m);
  }
  cm[(size_t)b * S + s]   = m;
  cinv[(size_t)b * S + s] = 1.f / sum;   // sum >= 1 (diagonal element)
}

// ---------------------------------------------------------------------------
// zero out (out is atomically accumulated)
// ---------------------------------------------------------------------------
__global__ void zero_out_kernel(float* __restrict__ out)
{
  const size_t idx = (size_t)blockIdx.x * 256 + threadIdx.x;
  ((float4*)out)[idx] = float4{0.f, 0.f, 0.f, 0.f};
}

// ---------------------------------------------------------------------------
// Kernel D: fused normalize + write att + partial att@v with atomicAdd.
// Block = 64 q-rows x 256 s-cols (4 sub-tiles of 64). Grid (8, 32, B).
// ---------------------------------------------------------------------------
__global__ __launch_bounds__(256) void norm_out_kernel(
    float* __restrict__ att, const float* __restrict__ qkv,
    const float* __restrict__ cm, const float* __restrict__ cinv,
    float* __restrict__ out)
{
  const int ch = blockIdx.x, qt = blockIdx.y, b = blockIdx.z;
  const int q0 = qt * 64, sbase = ch * 256;
  float* attb = att + (size_t)b * S * S;
  const float* vm = qkv + 2ull * BS * DK + (size_t)b * S * DK;

  __shared__ float As[64][68];     // normalized att sub-tile
  __shared__ float Vs[64][132];    // v sub-tile

  const int t  = threadIdx.x;
  const int nr = t >> 4;           // normalize phase: base row 0..15
  const int c4 = (t & 15) * 4;     // normalize phase: col group
  const int ry = t >> 5, cx = t & 31;  // GEMM: rows ry*8+i, cols cx*4..+3

  const bool did = (sbase <= q0 + 63);
  float4 acc4[8] = {};

  for (int sub = 0; sub < 4; ++sub) {
    const int s0 = sbase + sub * 64;
    const bool any = (s0 <= q0 + 63);

    if (any) {
      const float4 cmv = *(const float4*)&cm[(size_t)b * S + s0 + c4];
      const float4 civ = *(const float4*)&cinv[(size_t)b * S + s0 + c4];
      #pragma unroll
      for (int rr = 0; rr < 4; ++rr) {
        const int q = q0 + nr + 16 * rr;
        const size_t gi = (size_t)q * S + s0 + c4;
        const float4 raw = *(const float4*)&attb[gi];
        float4 x;
        x.x = (q >= s0 + c4 + 0) ? __expf(raw.x - cmv.x) * civ.x : 0.f;
        x.y = (q >= s0 + c4 + 1) ? __expf(raw.y - cmv.y) * civ.y : 0.f;
        x.z = (q >= s0 + c4 + 2) ? __expf(raw.z - cmv.z) * civ.z : 0.f;
        x.w = (q >= s0 + c4 + 3) ? __expf(raw.w - cmv.w) * civ.w : 0.f;
        *(float4*)&attb[gi] = x;
        *(float4*)&As[nr + 16 * rr][c4] = x;
      }
      // stage v sub-tile [64][128]
      #pragma unroll
      for (int i = 0; i < 8; ++i) {
        const int flat = t + i * 256;
        const int row = flat >> 5, vc4 = (flat & 31) * 4;
        *(float4*)&Vs[row][vc4] = *(const float4*)&vm[(size_t)(s0 + row) * DK + vc4];
      }
    } else {
      const float4 z = {0.f, 0.f, 0.f, 0.f};
      #pragma unroll
      for (int rr = 0; rr < 4; ++rr)
        *(float4*)&attb[(size_t)(q0 + nr + 16 * rr) * S + s0 + c4] = z;
    }
    __syncthreads();

    if (any) {
      #pragma unroll 2
      for (int kk = 0; kk < 64; kk += 4) {
        const float4 v0 = *(const float4*)&Vs[kk + 0][cx * 4];
        const float4 v1 = *(const float4*)&Vs[kk + 1][cx * 4];
        const float4 v2 = *(const float4*)&Vs[kk + 2][cx * 4];
        const float4 v3 = *(const float4*)&Vs[kk + 3][cx * 4];
        #pragma unroll
        for (int i = 0; i < 8; ++i) {
          const float4 a4 = *(const float4*)&As[ry * 8 + i][kk];
          acc4[i].x += a4.x * v0.x; acc4[i].y += a4.x * v0.y; acc4[i].z += a4.x * v0.z; acc4[i].w += a4.x * v0.w;
          acc4[i].x += a4.y * v1.x; acc4[i].y += a4.y * v1.y; acc4[i].z += a4.y * v1.z; acc4[i].w += a4.y * v1.w;
          acc4[i].x += a4.z * v2.x; acc4[i].y += a4.z * v2.y; acc4[i].z += a4.z * v2.z; acc4[i].w += a4.z * v2.w;
          acc4[i].x += a4.w * v3.x; acc4[i].y += a4.w * v3.y; acc4[i].z += a4.w * v3.z; acc4[i].w += a4.w * v3.w;
        }
      }
    }
    __syncthreads();
  }

  if (did) {
    #pragma unroll
    for (int i = 0; i < 8; ++i) {
      float* dst = &out[((size_t)b * S + q0 + ry * 8 + i) * DK + cx * 4];
      atomicAdd(dst + 0, acc4[i].x);
      atomicAdd(dst + 1, acc4[i].y);
      atomicAdd(dst + 2, acc4[i].z);
      atomicAdd(dst + 3, acc4[i].w);
    }
  }
}

// ---------------------------------------------------------------------------
extern "C" void kernel_launch(void* const* d_in, const int* in_sizes, int n_in,
                              void* d_out, int out_size, void* d_ws, size_t ws_size,
                              hipStream_t stream)
{
  const float* vin = (const float*)d_in[0];
  const float* wq  = (const float*)d_in[1];
  const float* wk  = (const float*)d_in[2];
  const float* wv  = (const float*)d_in[3];

  float* out = (float*)d_out;
  float* att = out + (size_t)B * S * DK;     // attention output region (64 MB)

  // bf16 copies live INSIDE the att region (dead before scores_kernel writes it)
  unsigned short* Ah  = (unsigned short*)att;
  unsigned short* Al  = Ah  + (size_t)BS * DM;
  unsigned short* Wth = Al  + (size_t)BS * DM;
  unsigned short* Wtl = Wth + (size_t)384 * DM;

  float* qkv  = (float*)d_ws;                // 3 * BS * 128 fp32 (12.6 MB)
  float* pm   = qkv + 3ull * BS * DK;        // B * 32 * S (1 MB)
  float* ps   = pm + 32ull * B * S;          // B * 32 * S (1 MB)
  float* cm   = ps + 32ull * B * S;          // B * S
  float* cinv = cm + (size_t)B * S;          // B * S

  cvt_hilo         <<<dim3(BS * DM / 1024),     256, 0, stream>>>(vin, Ah, Al);
  cvtw_kernel      <<<dim3(384),                256, 0, stream>>>(wq, wk, wv, Wth, Wtl);
  proj_mfma        <<<dim3(128, 6),             256, 0, stream>>>(Ah, Al, Wth, Wtl, qkv);
  zero_out_kernel  <<<dim3(BS * DK / 1024),     256, 0, stream>>>(out);
  scores_kernel    <<<dim3(S / 64, S / 64, B),  256, 0, stream>>>(qkv, att, pm, ps);
  colcombine_kernel<<<dim3(S / 256, B),         256, 0, stream>>>(pm, ps, cm, cinv);
  norm_out_kernel  <<<dim3(8, S / 64, B),       256, 0, stream>>>(att, qkv, cm, cinv, out);
}

// Round 6
// 131.341 us; speedup vs baseline: 2.3852x; 1.9186x over previous
//
#include <hip/hip_runtime.h>
#include <math.h>

// Problem constants
constexpr int B  = 4;
constexpr int S  = 2048;
constexpr int DM = 1024;
constexpr int DK = 128;
constexpr int BS = B * S;

static constexpr float SCALE = 0.08838834764831845f; // 1/sqrt(128)

typedef __attribute__((ext_vector_type(8))) short bf16x8;
typedef __attribute__((ext_vector_type(4))) float f32x4;
typedef __attribute__((ext_vector_type(8))) unsigned short u16x8;

__device__ __forceinline__ unsigned short f2bf(float x) {
  unsigned u = __float_as_uint(x);
  unsigned r = (u + 0x7FFFu + ((u >> 16) & 1u)) >> 16;   // RNE
  return (unsigned short)r;
}
__device__ __forceinline__ float bf2f(unsigned short h) {
  return __uint_as_float(((unsigned)h) << 16);
}

__device__ __forceinline__ void gload16(const void* g, void* l) {
  __builtin_amdgcn_global_load_lds(
      (const __attribute__((address_space(1))) void*)g,
      (__attribute__((address_space(3))) void*)l, 16, 0, 0);
}

// ---------------------------------------------------------------------------
// Prep 1: vin fp32 -> Ah (bf16 RNE) + Al (bf16 of residual), row-major [BS][DM]
// ---------------------------------------------------------------------------
__global__ __launch_bounds__(256) void cvt_hilo(
    const float* __restrict__ x, unsigned short* __restrict__ hi,
    unsigned short* __restrict__ lo)
{
  const size_t idx = (size_t)blockIdx.x * 256 + threadIdx.x;  // float4 index
  const float4 v = ((const float4*)x)[idx];
  ushort4 h, l;
  h.x = f2bf(v.x); l.x = f2bf(v.x - bf2f(h.x));
  h.y = f2bf(v.y); l.y = f2bf(v.y - bf2f(h.y));
  h.z = f2bf(v.z); l.z = f2bf(v.z - bf2f(h.z));
  h.w = f2bf(v.w); l.w = f2bf(v.w - bf2f(h.w));
  ((ushort4*)hi)[idx] = h;
  ((ushort4*)lo)[idx] = l;
}

// ---------------------------------------------------------------------------
// Prep 2: w_q/w_k/w_v [1024][128] fp32 -> Wt hi/lo bf16 [384][1024] (B^T)
// ---------------------------------------------------------------------------
__global__ void cvtw_kernel(const float* __restrict__ wq, const float* __restrict__ wk,
                            const float* __restrict__ wv,
                            unsigned short* __restrict__ Wth, unsigned short* __restrict__ Wtl)
{
  const int n = blockIdx.x;            // 0..383
  const int p = n >> 7, c = n & 127;
  const float* w = (p == 0) ? wq : (p == 1) ? wk : wv;
  for (int k = threadIdx.x; k < DM; k += 256) {
    const float x = w[(size_t)k * DK + c];
    const unsigned short h = f2bf(x);
    Wth[(size_t)n * DM + k] = h;
    Wtl[(size_t)n * DM + k] = f2bf(x - bf2f(h));
  }
}

// ---------------------------------------------------------------------------
// Kernel A: projections via split-bf16 MFMA. Emits q,k as bf16 hi/lo pairs
// [BS][128] and v as fp32 [BS][128]. XOR-swizzled LDS (T2, src-side).
// ---------------------------------------------------------------------------
__global__ __launch_bounds__(256) void proj_mfma(
    const unsigned short* __restrict__ Ah, const unsigned short* __restrict__ Al,
    const unsigned short* __restrict__ Wh, const unsigned short* __restrict__ Wl,
    unsigned short* __restrict__ qh, unsigned short* __restrict__ ql,
    unsigned short* __restrict__ kh, unsigned short* __restrict__ kl,
    float* __restrict__ vtmp)
{
  __shared__ unsigned short Ash[2][64 * 64];
  __shared__ unsigned short Wsh[2][64 * 64];

  const int r0 = blockIdx.x * 64;      // M tile
  const int n0 = blockIdx.y * 64;      // N tile (384/64 = 6)
  const int t  = threadIdx.x;
  const int l  = t & 63, w = t >> 6;
  const int wm = w >> 1, wn = w & 1;   // 2x2 wave grid
  const int fr = l & 15, kg = l >> 4;  // fragment row / k-group

  f32x4 acc[2][2] = {};

  for (int k0 = 0; k0 < DM; k0 += 64) {
    #pragma unroll
    for (int i = 0; i < 2; ++i) {
      const int flat = t + i * 256;          // 512 16B segments per tile
      const int row = flat >> 3, sg = flat & 7;
      const int sgs = sg ^ (row & 7);        // pre-swizzled source (T2)
      const size_t ga = (size_t)(r0 + row) * DM + k0 + sgs * 8;
      const size_t gw = (size_t)(n0 + row) * DM + k0 + sgs * 8;
      gload16(Ah + ga, &Ash[0][flat * 8]);
      gload16(Al + ga, &Ash[1][flat * 8]);
      gload16(Wh + gw, &Wsh[0][flat * 8]);
      gload16(Wl + gw, &Wsh[1][flat * 8]);
    }
    __syncthreads();

    #pragma unroll
    for (int kk = 0; kk < 2; ++kk) {
      bf16x8 ah[2], al[2], bh[2], bl[2];
      #pragma unroll
      for (int im = 0; im < 2; ++im) {
        const int row = wm * 32 + im * 16 + fr;
        const int off = row * 64 + ((kk * 4 + kg) ^ (row & 7)) * 8;
        ah[im] = *(const bf16x8*)&Ash[0][off];
        al[im] = *(const bf16x8*)&Ash[1][off];
      }
      #pragma unroll
      for (int in = 0; in < 2; ++in) {
        const int row = wn * 32 + in * 16 + fr;
        const int off = row * 64 + ((kk * 4 + kg) ^ (row & 7)) * 8;
        bh[in] = *(const bf16x8*)&Wsh[0][off];
        bl[in] = *(const bf16x8*)&Wsh[1][off];
      }
      #pragma unroll
      for (int im = 0; im < 2; ++im)
        #pragma unroll
        for (int in = 0; in < 2; ++in) {
          acc[im][in] = __builtin_amdgcn_mfma_f32_16x16x32_bf16(ah[im], bh[in], acc[im][in], 0, 0, 0);
          acc[im][in] = __builtin_amdgcn_mfma_f32_16x16x32_bf16(ah[im], bl[in], acc[im][in], 0, 0, 0);
          acc[im][in] = __builtin_amdgcn_mfma_f32_16x16x32_bf16(al[im], bh[in], acc[im][in], 0, 0, 0);
        }
    }
    __syncthreads();
  }

  // Epilogue: C/D layout col = lane&15, row = (lane>>4)*4 + reg
  const int crow = kg * 4;
  #pragma unroll
  for (int im = 0; im < 2; ++im)
    #pragma unroll
    for (int in = 0; in < 2; ++in) {
      const int n = n0 + wn * 32 + in * 16 + fr;
      const int p = n >> 7, c = n & 127;           // p uniform per block
      #pragma unroll
      for (int r = 0; r < 4; ++r) {
        const int m = r0 + wm * 32 + im * 16 + crow + r;
        const float val = acc[im][in][r];
        if (p == 2) {
          vtmp[(size_t)m * DK + c] = val;
        } else {
          const unsigned short h = f2bf(val);
          const unsigned short lo2 = f2bf(val - bf2f(h));
          unsigned short* hd = p ? kh : qh;
          unsigned short* ld = p ? kl : ql;
          hd[(size_t)m * DK + c] = h;
          ld[(size_t)m * DK + c] = lo2;
        }
      }
    }
}

// ---------------------------------------------------------------------------
// Prep 3: transpose v fp32 [B][S][128] -> vT hi/lo bf16 [B][128][S]
// ---------------------------------------------------------------------------
__global__ __launch_bounds__(256) void cvtv_kernel(
    const float* __restrict__ v, unsigned short* __restrict__ vTh,
    unsigned short* __restrict__ vTl)
{
  const int s0 = blockIdx.x * 64, d0 = blockIdx.y * 64, b = blockIdx.z;
  __shared__ float Ts[64][65];
  const int t = threadIdx.x;
  const int r = t >> 4, c4 = (t & 15) * 4;
  #pragma unroll
  for (int rr = 0; rr < 4; ++rr) {
    const int sl = r + 16 * rr;
    *(float4*)&Ts[sl][c4] =
        *(const float4*)&v[((size_t)b * S + s0 + sl) * DK + d0 + c4];
  }
  __syncthreads();
  const int dl = t >> 2, sq = (t & 3) * 16;
  unsigned short hbuf[16], lbuf[16];
  #pragma unroll
  for (int j = 0; j < 16; ++j) {
    const float val = Ts[sq + j][dl];
    hbuf[j] = f2bf(val);
    lbuf[j] = f2bf(val - bf2f(hbuf[j]));
  }
  const size_t o = (size_t)b * DK * S + (size_t)(d0 + dl) * S + s0 + sq;
  #pragma unroll
  for (int half = 0; half < 2; ++half) {
    *(u16x8*)&vTh[o + half * 8] = *(u16x8*)&hbuf[half * 8];
    *(u16x8*)&vTl[o + half * 8] = *(u16x8*)&lbuf[half * 8];
  }
}

// ---------------------------------------------------------------------------
// Kernel B: raw scores (split-bf16 MFMA) + fused per-64-chunk column stats.
// ---------------------------------------------------------------------------
__global__ __launch_bounds__(256) void scores_mfma(
    const unsigned short* __restrict__ qh, const unsigned short* __restrict__ ql,
    const unsigned short* __restrict__ kh, const unsigned short* __restrict__ kl,
    float* __restrict__ att, float* __restrict__ pm, float* __restrict__ ps)
{
  const int st = blockIdx.x, qt = blockIdx.y, b = blockIdx.z;
  if (qt < st) return;
  const int q0 = qt * 64, s0 = st * 64;

  __shared__ unsigned short Qh_s[64 * 128], Ql_s[64 * 128];
  __shared__ unsigned short Kh_s[64 * 128], Kl_s[64 * 128];
  __shared__ float SmL[64 * 2], SeL[64 * 2];

  const int t = threadIdx.x;
  const int l = t & 63, w = t >> 6;
  const int wm = w >> 1, wn = w & 1;
  const int fr = l & 15, kg = l >> 4;

  // stage q/k hi/lo tiles, pre-swizzled source (16 segs/row)
  #pragma unroll
  for (int i = 0; i < 4; ++i) {
    const int flat = t + i * 256;
    const int row = flat >> 4, sg = flat & 15;
    const int sgs = sg ^ (row & 7);
    const size_t gq = (size_t)(b * S + q0 + row) * DK + sgs * 8;
    const size_t gk = (size_t)(b * S + s0 + row) * DK + sgs * 8;
    gload16(qh + gq, &Qh_s[flat * 8]);
    gload16(ql + gq, &Ql_s[flat * 8]);
    gload16(kh + gk, &Kh_s[flat * 8]);
    gload16(kl + gk, &Kl_s[flat * 8]);
  }
  __syncthreads();

  f32x4 acc[2][2] = {};
  #pragma unroll
  for (int ks = 0; ks < 4; ++ks) {
    bf16x8 ah[2], al[2], bh[2], bl[2];
    #pragma unroll
    for (int im = 0; im < 2; ++im) {
      const int row = wm * 32 + im * 16 + fr;
      const int off = row * 128 + ((ks * 4 + kg) ^ (row & 7)) * 8;
      ah[im] = *(const bf16x8*)&Qh_s[off];
      al[im] = *(const bf16x8*)&Ql_s[off];
    }
    #pragma unroll
    for (int in = 0; in < 2; ++in) {
      const int row = wn * 32 + in * 16 + fr;
      const int off = row * 128 + ((ks * 4 + kg) ^ (row & 7)) * 8;
      bh[in] = *(const bf16x8*)&Kh_s[off];
      bl[in] = *(const bf16x8*)&Kl_s[off];
    }
    #pragma unroll
    for (int im = 0; im < 2; ++im)
      #pragma unroll
      for (int in = 0; in < 2; ++in) {
        acc[im][in] = __builtin_amdgcn_mfma_f32_16x16x32_bf16(ah[im], bh[in], acc[im][in], 0, 0, 0);
        acc[im][in] = __builtin_amdgcn_mfma_f32_16x16x32_bf16(ah[im], bl[in], acc[im][in], 0, 0, 0);
        acc[im][in] = __builtin_amdgcn_mfma_f32_16x16x32_bf16(al[im], bh[in], acc[im][in], 0, 0, 0);
      }
  }

  // scale + write raw scores
  float* attb = att + (size_t)b * S * S;
  #pragma unroll
  for (int im = 0; im < 2; ++im)
    #pragma unroll
    for (int in = 0; in < 2; ++in) {
      const int scol = s0 + wn * 32 + in * 16 + fr;
      #pragma unroll
      for (int r = 0; r < 4; ++r) {
        acc[im][in][r] *= SCALE;
        const int q = q0 + wm * 32 + im * 16 + kg * 4 + r;
        attb[(size_t)q * S + scol] = acc[im][in][r];
      }
    }

  // fused column stats (softmax over q within this 64-row chunk)
  const bool diag = (st == qt);
  float Sm_[2], Se_[2];
  #pragma unroll
  for (int in = 0; in < 2; ++in) {
    const int scol = s0 + wn * 32 + in * 16 + fr;
    float m8 = -INFINITY;
    #pragma unroll
    for (int im = 0; im < 2; ++im)
      #pragma unroll
      for (int r = 0; r < 4; ++r) {
        const int q = q0 + wm * 32 + im * 16 + kg * 4 + r;
        if (!diag || q >= scol) m8 = fmaxf(m8, acc[im][in][r]);
      }
    float e8 = 0.f;
    if (m8 > -INFINITY) {
      #pragma unroll
      for (int im = 0; im < 2; ++im)
        #pragma unroll
        for (int r = 0; r < 4; ++r) {
          const int q = q0 + wm * 32 + im * 16 + kg * 4 + r;
          if (!diag || q >= scol) e8 += __expf(acc[im][in][r] - m8);
        }
    }
    #pragma unroll
    for (int off = 16; off <= 32; off <<= 1) {
      const float om = __shfl_xor(m8, off);
      const float oe = __shfl_xor(e8, off);
      const float nm = fmaxf(m8, om);
      float ne = 0.f;
      if (m8 > -INFINITY) ne += e8 * __expf(m8 - nm);
      if (om > -INFINITY) ne += oe * __expf(om - nm);
      m8 = nm; e8 = ne;
    }
    Sm_[in] = m8; Se_[in] = e8;
  }
  if (l < 16) {
    #pragma unroll
    for (int in = 0; in < 2; ++in) {
      const int col = wn * 32 + in * 16 + l;
      SmL[col * 2 + wm] = Sm_[in];
      SeL[col * 2 + wm] = Se_[in];
    }
  }
  __syncthreads();
  if (t < 64) {
    const float m0 = SmL[t * 2 + 0], m1 = SmL[t * 2 + 1];
    const float nm = fmaxf(m0, m1);
    float ne = 0.f;
    if (m0 > -INFINITY) ne += SeL[t * 2 + 0] * __expf(m0 - nm);
    if (m1 > -INFINITY) ne += SeL[t * 2 + 1] * __expf(m1 - nm);
    const size_t o = ((size_t)(b * 32 + qt)) * S + s0 + t;
    pm[o] = nm;
    ps[o] = ne;
  }
}

// ---------------------------------------------------------------------------
// Kernel C: combine 32 row-chunk partials -> per-column max m and 1/sum.
// ---------------------------------------------------------------------------
__global__ void colcombine_kernel(const float* __restrict__ pm, const float* __restrict__ ps,
                                  float* __restrict__ cm, float* __restrict__ cinv)
{
  const int s = blockIdx.x * 256 + threadIdx.x;
  const int b = blockIdx.y;
  const int ch0 = s >> 6;
  float m = -INFINITY;
  for (int ch = ch0; ch < 32; ++ch)
    m = fmaxf(m, pm[((size_t)(b * 32 + ch)) * S + s]);
  float sum = 0.f;
  for (int ch = ch0; ch < 32; ++ch) {
    const size_t i = ((size_t)(b * 32 + ch)) * S + s;
    sum += ps[i] * __expf(pm[i] - m);
  }
  cm[(size_t)b * S + s]   = m;
  cinv[(size_t)b * S + s] = 1.f / sum;   // sum >= 1 (diagonal element)
}

// ---------------------------------------------------------------------------
// zero out (out is atomically accumulated)
// ---------------------------------------------------------------------------
__global__ void zero_out_kernel(float* __restrict__ out)
{
  const size_t idx = (size_t)blockIdx.x * 256 + threadIdx.x;
  ((float4*)out)[idx] = float4{0.f, 0.f, 0.f, 0.f};
}

// ---------------------------------------------------------------------------
// Kernel D: normalize (read raw, write fp32 att) + PV via split-bf16 MFMA.
// Block = 64 q-rows x 256 s-cols (4 sub-tiles). Grid (8, 32, B).
// ---------------------------------------------------------------------------
__global__ __launch_bounds__(256) void norm_out_mfma(
    float* __restrict__ att, const unsigned short* __restrict__ vTh,
    const unsigned short* __restrict__ vTl,
    const float* __restrict__ cm, const float* __restrict__ cinv,
    float* __restrict__ out)
{
  const int ch = blockIdx.x, qt = blockIdx.y, b = blockIdx.z;
  const int q0 = qt * 64, sbase = ch * 256;
  float* attb = att + (size_t)b * S * S;
  const unsigned short* vth = vTh + (size_t)b * DK * S;
  const unsigned short* vtl = vTl + (size_t)b * DK * S;

  __shared__ unsigned short Ash[64 * 64], Asl[64 * 64];   // att tile hi/lo (swz)
  __shared__ unsigned short Vsh[128 * 64], Vsl[128 * 64]; // vT tile hi/lo (swz)

  const int t = threadIdx.x;
  const int l = t & 63, w = t >> 6;
  const int nr = t >> 4, c4 = (t & 15) * 4;   // normalize phase
  const int fr = l & 15, kg = l >> 4;         // MFMA phase

  const bool anyblock = (sbase <= q0 + 63);
  f32x4 acc[8] = {};

  for (int sub = 0; sub < 4; ++sub) {
    const int s0 = sbase + sub * 64;
    if (s0 > q0 + 63) {
      // fully masked: write zeros
      const float4 z = {0.f, 0.f, 0.f, 0.f};
      #pragma unroll
      for (int rr = 0; rr < 4; ++rr)
        *(float4*)&attb[(size_t)(q0 + nr + 16 * rr) * S + s0 + c4] = z;
      continue;
    }

    // stage vT hi/lo tiles [128][64] (pre-swizzled source)
    #pragma unroll
    for (int i = 0; i < 4; ++i) {
      const int flat = t + i * 256;
      const int row = flat >> 3, sg = flat & 7;
      const int sgs = sg ^ (row & 7);
      const size_t gv = (size_t)row * S + s0 + sgs * 8;
      gload16(vth + gv, &Vsh[flat * 8]);
      gload16(vtl + gv, &Vsl[flat * 8]);
    }

    // normalize: read raw, write fp32 att, push bf16 hi/lo into LDS
    {
      const float4 cmv = *(const float4*)&cm[(size_t)b * S + s0 + c4];
      const float4 civ = *(const float4*)&cinv[(size_t)b * S + s0 + c4];
      #pragma unroll
      for (int rr = 0; rr < 4; ++rr) {
        const int qloc = nr + 16 * rr;
        const int q = q0 + qloc;
        const size_t gi = (size_t)q * S + s0 + c4;
        const float4 raw = *(const float4*)&attb[gi];
        float4 x;
        x.x = (q >= s0 + c4 + 0) ? __expf(raw.x - cmv.x) * civ.x : 0.f;
        x.y = (q >= s0 + c4 + 1) ? __expf(raw.y - cmv.y) * civ.y : 0.f;
        x.z = (q >= s0 + c4 + 2) ? __expf(raw.z - cmv.z) * civ.z : 0.f;
        x.w = (q >= s0 + c4 + 3) ? __expf(raw.w - cmv.w) * civ.w : 0.f;
        *(float4*)&attb[gi] = x;
        ushort4 h, lo4;
        h.x = f2bf(x.x); lo4.x = f2bf(x.x - bf2f(h.x));
        h.y = f2bf(x.y); lo4.y = f2bf(x.y - bf2f(h.y));
        h.z = f2bf(x.z); lo4.z = f2bf(x.z - bf2f(h.z));
        h.w = f2bf(x.w); lo4.w = f2bf(x.w - bf2f(h.w));
        const int idx = qloc * 64 + ((c4 >> 3) ^ (qloc & 7)) * 8 + (c4 & 7);
        *(ushort4*)&Ash[idx] = h;
        *(ushort4*)&Asl[idx] = lo4;
      }
    }
    __syncthreads();

    // PV: wave w computes q rows [w*16, w*16+16), all 128 d cols
    #pragma unroll
    for (int ks = 0; ks < 2; ++ks) {
      const int arow = w * 16 + fr;
      const int aoff = arow * 64 + ((ks * 4 + kg) ^ (arow & 7)) * 8;
      const bf16x8 a_h = *(const bf16x8*)&Ash[aoff];
      const bf16x8 a_l = *(const bf16x8*)&Asl[aoff];
      #pragma unroll
      for (int in = 0; in < 8; ++in) {
        const int brow = in * 16 + fr;
        const int boff = brow * 64 + ((ks * 4 + kg) ^ (brow & 7)) * 8;
        const bf16x8 b_h = *(const bf16x8*)&Vsh[boff];
        const bf16x8 b_l = *(const bf16x8*)&Vsl[boff];
        acc[in] = __builtin_amdgcn_mfma_f32_16x16x32_bf16(a_h, b_h, acc[in], 0, 0, 0);
        acc[in] = __builtin_amdgcn_mfma_f32_16x16x32_bf16(a_h, b_l, acc[in], 0, 0, 0);
        acc[in] = __builtin_amdgcn_mfma_f32_16x16x32_bf16(a_l, b_h, acc[in], 0, 0, 0);
      }
    }
    __syncthreads();
  }

  if (anyblock) {
    #pragma unroll
    for (int in = 0; in < 8; ++in) {
      #pragma unroll
      for (int r = 0; r < 4; ++r) {
        const int q = q0 + w * 16 + kg * 4 + r;
        const int d = in * 16 + fr;
        atomicAdd(&out[((size_t)b * S + q) * DK + d], acc[in][r]);
      }
    }
  }
}

// ---------------------------------------------------------------------------
extern "C" void kernel_launch(void* const* d_in, const int* in_sizes, int n_in,
                              void* d_out, int out_size, void* d_ws, size_t ws_size,
                              hipStream_t stream)
{
  const float* vin = (const float*)d_in[0];
  const float* wq  = (const float*)d_in[1];
  const float* wk  = (const float*)d_in[2];
  const float* wv  = (const float*)d_in[3];

  float* out = (float*)d_out;
  float* att = out + (size_t)B * S * DK;     // attention output region (64 MB)

  // bf16 copies of vin / W live INSIDE the att region (dead before scores writes)
  unsigned short* Ah  = (unsigned short*)att;
  unsigned short* Al  = Ah  + (size_t)BS * DM;
  unsigned short* Wth = Al  + (size_t)BS * DM;
  unsigned short* Wtl = Wth + (size_t)384 * DM;

  // d_ws: q/k hi/lo + vT hi/lo (12 MB) + 4 MB region shared by
  // vtmp (fp32 v, dead after cvtv) and softmax stats (written after).
  constexpr size_t NE = (size_t)BS * DK;     // 1048576
  unsigned short* qh  = (unsigned short*)d_ws;
  unsigned short* ql  = qh  + NE;
  unsigned short* kh  = ql  + NE;
  unsigned short* kl  = kh  + NE;
  unsigned short* vTh = kl  + NE;
  unsigned short* vTl = vTh + NE;
  float* vtmp = (float*)(vTl + NE);          // 4 MB
  float* pm   = vtmp;                        // aliases vtmp (v dead by then)
  float* ps   = pm + 32ull * B * S;          // 1 MB each
  float* cm   = ps + 32ull * B * S;
  float* cinv = cm + (size_t)B * S;

  cvt_hilo         <<<dim3(BS * DM / 1024),     256, 0, stream>>>(vin, Ah, Al);
  cvtw_kernel      <<<dim3(384),                256, 0, stream>>>(wq, wk, wv, Wth, Wtl);
  proj_mfma        <<<dim3(128, 6),             256, 0, stream>>>(Ah, Al, Wth, Wtl,
                                                                  qh, ql, kh, kl, vtmp);
  cvtv_kernel      <<<dim3(S / 64, 2, B),       256, 0, stream>>>(vtmp, vTh, vTl);
  zero_out_kernel  <<<dim3(BS * DK / 1024),     256, 0, stream>>>(out);
  scores_mfma      <<<dim3(S / 64, S / 64, B),  256, 0, stream>>>(qh, ql, kh, kl, att, pm, ps);
  colcombine_kernel<<<dim3(S / 256, B),         256, 0, stream>>>(pm, ps, cm, cinv);
  norm_out_mfma    <<<dim3(8, S / 64, B),       256, 0, stream>>>(att, vTh, vTl, cm, cinv, out);
}